// Round 19
// baseline (50.227 us; speedup 1.0000x reference)
//
#include <hip/hip_runtime.h>
#include <hip/hip_bf16.h>
#include <stdint.h>

// C[4096,10532] = inputs[4096,256] @ concat(lut,queue)[10532,256]^T  (fp32 out)
// R19 = R18 (persistent-B-in-regs, LDS-staged streaming-A, counted vmcnt,
// XCD-chunked swizzle) with B CONVERSION FUSED into the GEMM prologue:
//   - convert_kernel now converts ONLY inputs (4 MB fp32 -> 2 MB f16, ~1us)
//   - breg loads fp32 straight from lut/queue, converts in-reg (RNE casts),
//     zero-fills rows >= N_DIM (bn==41 tail)
// Removes the conv kernel's B round-trip (~16 MB traffic + ~4us wall).
// R11-calibrated model: gemm is near the ~5 TB/s mixed-stream regime
// (172 W + ~25 F MB ~= 40us); conv was the main reducible term left.

#define M_DIM 4096
#define K_DIM 256
#define N_LUT 5532
#define N_Q   5000
#define N_DIM (N_LUT + N_Q)   // 10532
#define BN    256
#define NT_N  42              // ceil(10532/256)
#define NSTRIP 6              // m-strips; 128 subtiles of 32 rows split 21/22

typedef _Float16 f16x8 __attribute__((ext_vector_type(8)));
typedef float f32x4 __attribute__((ext_vector_type(4)));

// ---------------- convert fp32 -> f16 (A only) ----------------
__global__ __launch_bounds__(256) void convert_kernel(
    const float* __restrict__ inp, unsigned short* __restrict__ Abf) {
  int i = blockIdx.x * 256 + threadIdx.x;  // 1024 blocks exact
  float4 x = ((const float4*)inp)[i];
  union { _Float16 h; unsigned short u; } a, b, c, d;
  a.h = (_Float16)x.x; b.h = (_Float16)x.y;
  c.h = (_Float16)x.z; d.h = (_Float16)x.w;
  ushort4 o; o.x = a.u; o.y = b.u; o.z = c.u; o.w = d.u;
  *(ushort4*)(Abf + i * 4) = o;
}

// ---------------- GEMM: persistent-B-in-regs, streaming-A ----------------
#define GLDS16(gsrc, ldst)                                                  \
  __builtin_amdgcn_global_load_lds(                                         \
      (__attribute__((address_space(1))) void*)(gsrc),                      \
      (__attribute__((address_space(3))) void*)(ldst), 16, 0, 0)

__global__ __launch_bounds__(512, 2) void gemm_kernel(
    const unsigned short* __restrict__ A, const float* __restrict__ lut,
    const float* __restrict__ que, float* __restrict__ C) {
  // A only: double-buffered 32 rows x 256 k = 2 x 16 KiB (B lives in VGPRs)
  __shared__ __align__(16) unsigned short As[2][32 * 256];

  const int t = threadIdx.x;
  const int lane = t & 63;
  const int wave = t >> 6;         // 8 waves; wave w owns C-cols w*32..+32

  // bijective XCD-chunked swizzle (m204): nwg=252, q=31, r=4; bn-fast order
  const int bid = blockIdx.x;
  const int xcd = bid & 7, idx = bid >> 3;
  const int wg = ((xcd < 4) ? xcd * 32 : 128 + (xcd - 4) * 31) + idx;
  const int s = wg / NT_N;         // strip 0..5
  const int bn = wg % NT_N;        // bn-fast within strip
  const int bcol = bn * BN;
  const bool fullN = (bcol + BN <= N_DIM);  // false only for bn==41
  // strips: subtile counts 21,21,21,21,22,22 (sum 128)
  const int csub = 21 + (s >= 4 ? 1 : 0);
  const int sub0 = 21 * s + (s >= 5 ? 1 : 0);   // s=5 starts at 106
  const int row0 = sub0 * 32;

  const int lr = lane & 15;
  const int rsw = lane & 7;        // = row&7 for all fragment rows
  const int cq = lane >> 4;        // 0..3
  const int cc4 = cq * 4;

  // ---- A staging geometry (rows of 256 f16 = 32 x 16B chunks) ----
  // swizzle: lds[row][c] = global[row][c ^ (row&7)]; staging thread t in
  // round r covers slot row = r*16 + (t>>5), chunk = t&31 -> fetch swizzled.
  const int srow = t >> 5;                        // 0..15 within round
  const int scs = (((t & 31) ^ (srow & 7)) * 8);  // swizzled col, elements
  const unsigned short* gaBase0 = A + (size_t)(row0 + srow) * K_DIM + scs;
  const int ldsRound = wave * 2 * 256;  // wave-uniform base per round (elems)

  // A subtile: 32 rows = 2 rounds of 16 (2 gload_lds per thread)
#define STAGE_A(buf, sub)                                                    \
  do {                                                                       \
    _Pragma("unroll") for (int r = 0; r < 2; ++r)                            \
      GLDS16(gaBase0 + ((size_t)(sub) * 32 + r * 16) * K_DIM,                \
             As[buf] + r * 16 * 256 + ldsRound);                             \
  } while (0)

  STAGE_A(0, 0);                   // issue early; latency hides under B-cvt

  // ---- persistent B fragments: fp32 from lut/queue -> f16 regs (64 VGPR) ----
  // breg[j][ks]: B-row = bcol + wave*32 + j*16 + lr, k = ks*32 + cq*8.
  f16x8 breg[2][8];
#pragma unroll
  for (int j = 0; j < 2; ++j) {
    const int row = bcol + wave * 32 + j * 16 + lr;
    const bool valid = row < N_DIM;
    const float* src = (row < N_LUT) ? (lut + (size_t)row * K_DIM)
                      : valid        ? (que + (size_t)(row - N_LUT) * K_DIM)
                                     : lut;  // safe dummy for OOB rows
#pragma unroll
    for (int ks = 0; ks < 8; ++ks) {
      const float* p = src + ks * 32 + cq * 8;
      f32x4 lo = *(const f32x4*)p;
      f32x4 hi = *(const f32x4*)(p + 4);
      if (!valid) {                // bn==41 tail rows -> zero
        lo = (f32x4){0.f, 0.f, 0.f, 0.f};
        hi = (f32x4){0.f, 0.f, 0.f, 0.f};
      }
      f16x8 v;
      v[0] = (_Float16)lo[0]; v[1] = (_Float16)lo[1];
      v[2] = (_Float16)lo[2]; v[3] = (_Float16)lo[3];
      v[4] = (_Float16)hi[0]; v[5] = (_Float16)hi[1];
      v[6] = (_Float16)hi[2]; v[7] = (_Float16)hi[3];
      breg[j][ks] = v;
    }
  }

  __syncthreads();                 // full drain + barrier (once)

  int cur = 0;
#pragma unroll 1
  for (int sub = 0; sub < csub; ++sub) {
    if (sub + 1 < csub)
      STAGE_A(cur ^ 1, sub + 1);   // 2 gload_lds: oldest in vmem queue
    __builtin_amdgcn_sched_barrier(0);  // pin loads ABOVE compute+stores

    f32x4 acc[2][2] = {};
#pragma unroll
    for (int ks = 0; ks < 8; ++ks) {           // K = 256 = 8 x 32
      const int ch = (ks * 4 + cq) ^ rsw;      // swizzled 16B chunk, 0..31
      f16x8 a[2];
#pragma unroll
      for (int i = 0; i < 2; ++i)
        a[i] = *(const f16x8*)&As[cur][(i * 16 + lr) * 256 + ch * 8];
      // swapped operands: C-row = i*16+lr, C-cols = j*16 + cc4 + reg
#pragma unroll
      for (int i = 0; i < 2; ++i)
#pragma unroll
        for (int j = 0; j < 2; ++j)
          acc[i][j] = __builtin_amdgcn_mfma_f32_16x16x32_f16(breg[j][ks], a[i],
                                                             acc[i][j], 0, 0, 0);
    }

    // 4 dwordx4 C-stores (newest in vmem queue; ride across the barrier)
#pragma unroll
    for (int i = 0; i < 2; ++i) {
      size_t rowBase = (size_t)(row0 + sub * 32 + i * 16 + lr) * N_DIM;
#pragma unroll
      for (int j = 0; j < 2; ++j) {
        int col = bcol + wave * 32 + j * 16 + cc4;
        if (col < N_DIM)           // N_DIM%4==0: granule fully valid
          *(f32x4*)&C[rowBase + col] = acc[i][j];
      }
    }

    if (sub + 1 < csub) {
      // counted wait: A(next) loads (older) complete; this subtile's 4
      // stores stay in flight and drain under next compute. vmcnt BEFORE
      // barrier (R2 race lesson). bn==41: store instr count varies -> 0.
      if (fullN)
        asm volatile("s_waitcnt vmcnt(4)" ::: "memory");
      else
        asm volatile("s_waitcnt vmcnt(0)" ::: "memory");
      asm volatile("s_barrier" ::: "memory");
    }
    cur ^= 1;
  }
#undef STAGE_A
}

extern "C" void kernel_launch(void* const* d_in, const int* in_sizes, int n_in,
                              void* d_out, int out_size, void* d_ws, size_t ws_size,
                              hipStream_t stream) {
  const float* inp = (const float*)d_in[0];   // inputs [4096,256]
  // d_in[1] targets, d_in[2] gt_flag: unused by the forward similarity
  const float* lut = (const float*)d_in[3];   // [5532,256]
  const float* que = (const float*)d_in[4];   // [5000,256]
  float* C = (float*)d_out;                   // [4096,10532]

  unsigned short* Abf = (unsigned short*)d_ws;  // 2 MB of ws

  const int conv_blocks = M_DIM * K_DIM / 4 / 256;  // 1024
  convert_kernel<<<conv_blocks, 256, 0, stream>>>(inp, Abf);

  gemm_kernel<<<NSTRIP * NT_N, 512, 0, stream>>>(Abf, lut, que, C);
}

// Round 21
// 47.635 us; speedup vs baseline: 1.0544x; 1.0544x over previous
//
#include <hip/hip_runtime.h>
#include <hip/hip_bf16.h>
#include <stdint.h>

// C[4096,10532] = inputs[4096,256] @ concat(lut,queue)[10532,256]^T  (fp32 out)
// R21 = R18 EXACT REVERT (best verified: 47.5us). R20's wave-decoupled
// variant failed correctness (unverifiable sync structure headlessly).
// R18: persistent-B-in-regs (64 VGPR), LDS-staged streaming-A double buffer,
// counted vmcnt(4) store-ride barrier, bijective XCD-chunked swizzle.
// This run is the reproducibility check before a roofline call: gemm ~41us
// == 197 MB at the twice-measured ~4.8 TB/s mixed/strided-write ceiling.

#define M_DIM 4096
#define K_DIM 256
#define N_LUT 5532
#define N_Q   5000
#define N_DIM (N_LUT + N_Q)   // 10532
#define BN    256
#define NT_N  42              // ceil(10532/256)
#define N_PAD (NT_N * 256)    // 10752
#define NSTRIP 6              // m-strips; 128 subtiles of 32 rows split 21/22

typedef _Float16 f16x8 __attribute__((ext_vector_type(8)));
typedef float f32x4 __attribute__((ext_vector_type(4)));

__device__ __forceinline__ unsigned short f2h(float f) {
  union { _Float16 h; unsigned short u; } v;
  v.h = (_Float16)f;   // v_cvt_f16_f32, RNE
  return v.u;
}

// ---------------- convert fp32 -> f16 into workspace ----------------
__global__ __launch_bounds__(256) void convert_kernel(
    const float* __restrict__ inp, const float* __restrict__ lut,
    const float* __restrict__ que, unsigned short* __restrict__ Abf,
    unsigned short* __restrict__ Bbf) {
  const int AV = M_DIM * K_DIM / 4;  // 262144 float4s for A
  int i = blockIdx.x * 256 + threadIdx.x;  // grid sized exactly
  float4 x;
  unsigned short* dst;
  if (i < AV) {
    x = ((const float4*)inp)[i];
    dst = Abf + i * 4;
  } else {
    int e = (i - AV) * 4;          // element index in padded B
    int row = e >> 8;              // /256
    int col = e & 255;
    if (row < N_LUT)
      x = *(const float4*)(lut + (size_t)row * K_DIM + col);
    else if (row < N_DIM)
      x = *(const float4*)(que + (size_t)(row - N_LUT) * K_DIM + col);
    else
      x = make_float4(0.f, 0.f, 0.f, 0.f);
    dst = Bbf + e;
  }
  ushort4 o;
  o.x = f2h(x.x); o.y = f2h(x.y); o.z = f2h(x.z); o.w = f2h(x.w);
  *(ushort4*)dst = o;
}

// ---------------- GEMM: persistent-B-in-regs, streaming-A ----------------
#define GLDS16(gsrc, ldst)                                                  \
  __builtin_amdgcn_global_load_lds(                                         \
      (__attribute__((address_space(1))) void*)(gsrc),                      \
      (__attribute__((address_space(3))) void*)(ldst), 16, 0, 0)

__global__ __launch_bounds__(512, 2) void gemm_kernel(
    const unsigned short* __restrict__ A, const unsigned short* __restrict__ B,
    float* __restrict__ C) {
  // A only: double-buffered 32 rows x 256 k = 2 x 16 KiB (B lives in VGPRs)
  __shared__ __align__(16) unsigned short As[2][32 * 256];

  const int t = threadIdx.x;
  const int lane = t & 63;
  const int wave = t >> 6;         // 8 waves; wave w owns C-cols w*32..+32

  // bijective XCD-chunked swizzle (m204): nwg=252, q=31, r=4; bn-fast order
  const int bid = blockIdx.x;
  const int xcd = bid & 7, idx = bid >> 3;
  const int wg = ((xcd < 4) ? xcd * 32 : 128 + (xcd - 4) * 31) + idx;
  const int s = wg / NT_N;         // strip 0..5
  const int bn = wg % NT_N;        // bn-fast within strip
  const int bcol = bn * BN;
  const bool fullN = (bcol + BN <= N_DIM);  // false only for bn==41
  // strips: subtile counts 21,21,21,21,22,22 (sum 128)
  const int csub = 21 + (s >= 4 ? 1 : 0);
  const int sub0 = 21 * s + (s >= 5 ? 1 : 0);   // s=5 starts at 106
  const int row0 = sub0 * 32;

  const int lr = lane & 15;
  const int rsw = lane & 7;        // = row&7 for all fragment rows
  const int cq = lane >> 4;        // 0..3
  const int cc4 = cq * 4;

  // ---- persistent B fragments -> registers (64 VGPR) ----
  // breg[j][ks]: B-row = bcol + wave*32 + j*16 + lr, k = ks*32 + cq*8.
  // Bbf padded/zeroed to N_PAD rows -> bn==41 loads in-bounds.
  f16x8 breg[2][8];
#pragma unroll
  for (int j = 0; j < 2; ++j) {
    const unsigned short* brow =
        B + (size_t)(bcol + wave * 32 + j * 16 + lr) * K_DIM + cq * 8;
#pragma unroll
    for (int ks = 0; ks < 8; ++ks)
      breg[j][ks] = *(const f16x8*)(brow + ks * 32);
  }

  // ---- A staging geometry (rows of 256 f16 = 32 x 16B chunks) ----
  // swizzle: lds[row][c] = global[row][c ^ (row&7)]; staging thread t in
  // round r covers slot row = r*16 + (t>>5), chunk = t&31 -> fetch swizzled.
  const int srow = t >> 5;                        // 0..15 within round
  const int scs = (((t & 31) ^ (srow & 7)) * 8);  // swizzled col, elements
  const unsigned short* gaBase0 = A + (size_t)(row0 + srow) * K_DIM + scs;
  const int ldsRound = wave * 2 * 256;  // wave-uniform base per round (elems)

  // A subtile: 32 rows = 2 rounds of 16 (2 gload_lds per thread)
#define STAGE_A(buf, sub)                                                    \
  do {                                                                       \
    _Pragma("unroll") for (int r = 0; r < 2; ++r)                            \
      GLDS16(gaBase0 + ((size_t)(sub) * 32 + r * 16) * K_DIM,                \
             As[buf] + r * 16 * 256 + ldsRound);                             \
  } while (0)

  STAGE_A(0, 0);
  __syncthreads();                 // full drain + barrier (once)

  int cur = 0;
#pragma unroll 1
  for (int sub = 0; sub < csub; ++sub) {
    if (sub + 1 < csub)
      STAGE_A(cur ^ 1, sub + 1);   // 2 gload_lds: oldest in vmem queue
    __builtin_amdgcn_sched_barrier(0);  // pin loads ABOVE compute+stores

    f32x4 acc[2][2] = {};
#pragma unroll
    for (int ks = 0; ks < 8; ++ks) {           // K = 256 = 8 x 32
      const int ch = (ks * 4 + cq) ^ rsw;      // swizzled 16B chunk, 0..31
      f16x8 a[2];
#pragma unroll
      for (int i = 0; i < 2; ++i)
        a[i] = *(const f16x8*)&As[cur][(i * 16 + lr) * 256 + ch * 8];
      // swapped operands: C-row = i*16+lr, C-cols = j*16 + cc4 + reg
#pragma unroll
      for (int i = 0; i < 2; ++i)
#pragma unroll
        for (int j = 0; j < 2; ++j)
          acc[i][j] = __builtin_amdgcn_mfma_f32_16x16x32_f16(breg[j][ks], a[i],
                                                             acc[i][j], 0, 0, 0);
    }

    // 4 dwordx4 C-stores (newest in vmem queue; ride across the barrier)
#pragma unroll
    for (int i = 0; i < 2; ++i) {
      size_t rowBase = (size_t)(row0 + sub * 32 + i * 16 + lr) * N_DIM;
#pragma unroll
      for (int j = 0; j < 2; ++j) {
        int col = bcol + wave * 32 + j * 16 + cc4;
        if (col < N_DIM)           // N_DIM%4==0: granule fully valid
          *(f32x4*)&C[rowBase + col] = acc[i][j];
      }
    }

    if (sub + 1 < csub) {
      // counted wait: A(next) loads (older) complete; this subtile's 4
      // stores stay in flight and drain under next compute. vmcnt BEFORE
      // barrier (R2 race lesson). bn==41: store instr count varies -> 0.
      if (fullN)
        asm volatile("s_waitcnt vmcnt(4)" ::: "memory");
      else
        asm volatile("s_waitcnt vmcnt(0)" ::: "memory");
      asm volatile("s_barrier" ::: "memory");
    }
    cur ^= 1;
  }
#undef STAGE_A
}

extern "C" void kernel_launch(void* const* d_in, const int* in_sizes, int n_in,
                              void* d_out, int out_size, void* d_ws, size_t ws_size,
                              hipStream_t stream) {
  const float* inp = (const float*)d_in[0];   // inputs [4096,256]
  // d_in[1] targets, d_in[2] gt_flag: unused by the forward similarity
  const float* lut = (const float*)d_in[3];   // [5532,256]
  const float* que = (const float*)d_in[4];   // [5000,256]
  float* C = (float*)d_out;                   // [4096,10532]

  unsigned short* Abf = (unsigned short*)d_ws;
  unsigned short* Bbf = Abf + (size_t)M_DIM * K_DIM;  // ~7.7 MB of ws

  const int conv_blocks = (M_DIM * K_DIM / 4 + N_PAD * K_DIM / 4) / 256;
  convert_kernel<<<conv_blocks, 256, 0, stream>>>(inp, lut, que, Abf, Bbf);

  gemm_kernel<<<NSTRIP * NT_N, 512, 0, stream>>>(Abf, Bbf, C);
}